// Round 10
// baseline (120.023 us; speedup 1.0000x reference)
//
#include <hip/hip_runtime.h>

typedef _Float16 f16;
typedef _Float16 f16x8 __attribute__((ext_vector_type(8)));
typedef _Float16 f16x4 __attribute__((ext_vector_type(4)));
typedef float    f32x4 __attribute__((ext_vector_type(4)));
typedef __fp16   fp16x2 __attribute__((ext_vector_type(2)));

#define MFMA(a,b,c) __builtin_amdgcn_mfma_f32_16x16x32_f16((a),(b),(c),0,0,0)

#if __has_builtin(__builtin_amdgcn_exp2f)
#define EXP2(x) __builtin_amdgcn_exp2f(x)
#else
#define EXP2(x) exp2f(x)
#endif

// async global->LDS, 16B per lane. ldsptr must be wave-uniform; lane i lands at ldsptr + i*16.
__device__ __forceinline__ void gl_lds16(const void* g, void* l) {
  __builtin_amdgcn_global_load_lds(
      (__attribute__((address_space(1))) void*)(void*)(g),
      (__attribute__((address_space(3))) void*)(l),
      16, 0, 0);
}

// LDS column swizzle: uses row bits 0,1,3 -> uniform 8-way 16B-unit spread for
// the rho-ordered kf reads.
__device__ __forceinline__ int SWZ(int row) {
  return ((row & 3) | ((row >> 1) & 4)) << 4;
}

// ---------------- kernel 0: fp32 -> fp16 conversion / packing ----------------
__global__ __launch_bounds__(256) void k_convert(
    const float* __restrict__ x, const float* __restrict__ Wq,
    const float* __restrict__ Wk, const float* __restrict__ Wv,
    const float* __restrict__ Wo,
    f16* __restrict__ x_h, f16* __restrict__ wqkv_h, f16* __restrict__ wo_h) {
  const int XQ    = (8192 * 512) / 4;
  const int WQKVQ = (1536 * 512) / 4;
  const int WOQ   = (512 * 512) / 4;
  const int total = XQ + WQKVQ + WOQ;
  for (int q = blockIdx.x * blockDim.x + threadIdx.x; q < total;
       q += gridDim.x * blockDim.x) {
    const float* src;
    f16* dst;
    if (q < XQ) {
      src = x + q * 4;
      dst = x_h + q * 4;
    } else if (q < XQ + WQKVQ) {
      int j  = q - XQ;
      int r  = j >> 7;
      int c0 = (j & 127) * 4;
      const float* w = (r < 512) ? Wq : (r < 1024) ? Wk : Wv;
      src = w + (r & 511) * 512 + c0;
      dst = wqkv_h + j * 4;
    } else {
      int j = q - XQ - WQKVQ;
      src = Wo + j * 4;
      dst = wo_h + j * 4;
    }
    float4 v = *(const float4*)src;
    f16x4 o = {(f16)v.x, (f16)v.y, (f16)v.z, (f16)v.w};
    *(f16x4*)dst = o;
  }
}

// ---------------- shared GEMM core: C(128x128) += A[128xK] * B[128xK]^T ------
// Double-buffered LDS, single barrier per K-step, stage issued under compute.
__device__ __forceinline__ void gemm_core(const f16* __restrict__ A,
                                          const f16* __restrict__ B,
                                          int bm, int bn, f32x4 (&acc)[4][4]) {
  __shared__ f16 As[2][128 * 64];
  __shared__ f16 Bs[2][128 * 64];
  const int tid  = threadIdx.x;
  const int lane = tid & 63;
  const int w    = tid >> 6;
  const int wr   = (w >> 1) & 1, wc = w & 1;
  const int r0   = tid >> 3;
  const int cb   = (tid & 7) << 4;

  auto stage = [&](int buf, int kt) {
#pragma unroll
    for (int inst = 0; inst < 4; ++inst) {
      const int row  = inst * 32 + r0;
      const int csrc = cb ^ ((row & 7) << 4);
      gl_lds16(A + (bm + row) * 512 + kt + (csrc >> 1),
               (char*)As[buf] + inst * 4096 + w * 1024);
      gl_lds16(B + (bn + row) * 512 + kt + (csrc >> 1),
               (char*)Bs[buf] + inst * 4096 + w * 1024);
    }
  };

  stage(0, 0);
#pragma unroll
  for (int t = 0; t < 8; ++t) {
    const int cur = t & 1;
    asm volatile("s_waitcnt vmcnt(0)" ::: "memory");
    __builtin_amdgcn_s_barrier();
    __builtin_amdgcn_sched_barrier(0);
    if (t < 7) stage(cur ^ 1, (t + 1) * 64);
    f16x8 af[4][2], bf[4][2];
#pragma unroll
    for (int i = 0; i < 4; ++i) {
      const int ra = wr * 64 + i * 16 + (lane & 15);
      const int rb = wc * 64 + i * 16 + (lane & 15);
#pragma unroll
      for (int ks = 0; ks < 2; ++ks) {
        const int cc = ks * 64 + ((lane >> 4) << 4);
        af[i][ks] = *(const f16x8*)((const char*)As[cur] + ra * 128 + (cc ^ ((ra & 7) << 4)));
        bf[i][ks] = *(const f16x8*)((const char*)Bs[cur] + rb * 128 + (cc ^ ((rb & 7) << 4)));
      }
    }
    __builtin_amdgcn_s_setprio(1);
#pragma unroll
    for (int i = 0; i < 4; ++i)
#pragma unroll
      for (int j = 0; j < 4; ++j) {
        acc[i][j] = MFMA(af[i][0], bf[j][0], acc[i][j]);
        acc[i][j] = MFMA(af[i][1], bf[j][1], acc[i][j]);
      }
    __builtin_amdgcn_s_setprio(0);
  }
}

// ---------------- kernel 1: QKV projection ----------------
// Q scaled by log2(e)/sqrt(512); Q,K -> [b,h,t,s]; V -> [b,h,s,t] (plain t).
__global__ __launch_bounds__(256) void k_gemm_qkv(
    const f16* __restrict__ A, const f16* __restrict__ B,
    f16* __restrict__ q_h, f16* __restrict__ k_h, f16* __restrict__ vt_h) {
  const int bm = blockIdx.x * 128;
  const int bn = blockIdx.y * 128;
  f32x4 acc[4][4] = {};
  gemm_core(A, B, bm, bn, acc);

  const int tid  = threadIdx.x;
  const int lane = tid & 63;
  const int w    = tid >> 6;
  const int wr   = (w >> 1) & 1, wc = w & 1;
  const float qscale = 0.044194173824159216f * 1.4426950408889634f;
#pragma unroll
  for (int i = 0; i < 4; ++i) {
    const int m0 = bm + wr * 64 + i * 16 + ((lane >> 4) << 2);
#pragma unroll
    for (int j = 0; j < 4; ++j) {
      const int n   = bn + wc * 64 + j * 16 + (lane & 15);
      const int sec = n >> 9;
      const int nn  = n & 511;
      const int h   = nn >> 6, s = nn & 63;
#pragma unroll
      for (int r = 0; r < 4; ++r) {
        const int m = m0 + r;
        const int b = m >> 11, t = m & 2047;
        const int bh = b * 8 + h;
        const float v = acc[i][j][r];
        if (sec == 0)
          q_h[(bh * 2048 + t) * 64 + s] = (f16)(v * qscale);
        else if (sec == 1)
          k_h[(bh * 2048 + t) * 64 + s] = (f16)v;
        else
          vt_h[(bh * 64 + s) * 2048 + t] = (f16)v;
      }
    }
  }
}

// ---------------- kernel 2: flash attention ----------------------------------
// In-register P (swapped QK^T + rho K-row order), K-split across 2 groups of
// 4 waves. This round: V read DIRECT from global (L1-resident tile; LDS holds
// K only), l accumulated on the VALU (no l-MFMA), 2 tiles per barrier with
// 4 K-buffers to widen the no-fence overlap window (anti-convoy).
__global__ __launch_bounds__(512, 2) void k_attn(
    const f16* __restrict__ q_h, const f16* __restrict__ k_h,
    const f16* __restrict__ vt_h, f16* __restrict__ a_h) {
  __shared__ char smem[65536];  // K: [g][buf0..3] 8x8KB; combine reuses 35.8KB

  const int tid  = threadIdx.x;
  const int lane = tid & 63;
  const int w    = tid >> 6;
  const int g    = w >> 2;   // k-half
  const int wg   = w & 3;    // wave within group

  int id = blockIdx.x;
  id = (id & 7) * 64 + (id >> 3);     // XCD chunking (512 = 8*64, bijective)
  const int qt = (id & 15) * 128;
  const int bh = id >> 4;

  const f16* qb = q_h + (size_t)bh * 2048 * 64;
  const f16* kb = k_h + (size_t)bh * 2048 * 64;
  const f16* vb = vt_h + (size_t)bh * 64 * 2048;

  auto KsP = [&](int grp, int buf) { return smem + (grp * 4 + buf) * 8192; };

  f16x8 qf[2][2];
#pragma unroll
  for (int i = 0; i < 2; ++i) {
    const int qrow = qt + wg * 32 + i * 16 + (lane & 15);
#pragma unroll
    for (int ks = 0; ks < 2; ++ks)
      qf[i][ks] = *(const f16x8*)(qb + qrow * 64 + ks * 32 + ((lane >> 4) << 3));
  }

  f32x4 oacc[2][4] = {};
  float lsum[2]    = {0.f, 0.f};

  const int gt  = tid & 255;        // group-local tid
  const int r0  = gt >> 3;          // 0..31
  const int cbb = (tid & 7) << 4;

  auto stage = [&](int buf, int t) {
    const int ktv = g * 1024 + t * 64;
#pragma unroll
    for (int inst = 0; inst < 2; ++inst) {
      const int row  = inst * 32 + r0;
      const int csrc = cbb ^ SWZ(row);
      gl_lds16(kb + (ktv + row) * 64 + (csrc >> 1),
               KsP(g, buf) + inst * 4096 + wg * 1024);
    }
  };

  auto pack4 = [](float a, float b, float c, float d) -> unsigned long long {
    union { fp16x2 h2[2]; unsigned long long u; } t;
    t.h2[0] = __builtin_amdgcn_cvt_pkrtz(a, b);
    t.h2[1] = __builtin_amdgcn_cvt_pkrtz(c, d);
    return t.u;
  };

  auto tile = [&](const char* ksb, int ktv) {
    const int m  = lane & 15;
    const int hi = lane >> 4;
    // V fragments direct from global (issue first; L1-resident, latency
    // covered by the K-LDS reads + QK MFMAs)
    f16x8 vf0[4], vf1[4];
#pragma unroll
    for (int n = 0; n < 4; ++n) {
      const f16* vrow = vb + (size_t)(n * 16 + m) * 2048 + ktv + hi * 8;
      vf0[n] = *(const f16x8*)(vrow);
      vf1[n] = *(const f16x8*)(vrow + 32);
    }
    // K fragments in rho order rho(n,m)=32(n>>1)+8(m>>2)+4(n&1)+(m&3)
    f16x8 kf[4][2];
#pragma unroll
    for (int n = 0; n < 4; ++n) {
      const int row = ((n >> 1) << 5) + ((m >> 2) << 3) + ((n & 1) << 2) + (m & 3);
      const int sw  = SWZ(row);
#pragma unroll
      for (int ks = 0; ks < 2; ++ks) {
        const int c = (ks * 64 + (hi << 4)) ^ sw;
        kf[n][ks] = *(const f16x8*)(ksb + row * 128 + c);
      }
    }
    // S^T = K Q^T (swapped operands)
    f32x4 sf[2][4];
    __builtin_amdgcn_s_setprio(1);
#pragma unroll
    for (int i = 0; i < 2; ++i)
#pragma unroll
      for (int n = 0; n < 4; ++n) {
        f32x4 s = {0.f, 0.f, 0.f, 0.f};
        s = MFMA(kf[n][0], qf[i][0], s);
        s = MFMA(kf[n][1], qf[i][1], s);
        sf[i][n] = s;
      }
    __builtin_amdgcn_s_setprio(0);
    // P = exp2(S) in-place; lsum on VALU; pack in-lane into PV A-fragments
    f16x8 pa[2][2];
#pragma unroll
    for (int i = 0; i < 2; ++i) {
#pragma unroll
      for (int n = 0; n < 4; ++n)
#pragma unroll
        for (int r = 0; r < 4; ++r) sf[i][n][r] = EXP2(sf[i][n][r]);
      const f32x4 ssum = (sf[i][0] + sf[i][1]) + (sf[i][2] + sf[i][3]);
      lsum[i] += (ssum[0] + ssum[1]) + (ssum[2] + ssum[3]);
#pragma unroll
      for (int ks = 0; ks < 2; ++ks) {
        union { unsigned long long u[2]; f16x8 v; } u;
        u.u[0] = pack4(sf[i][2 * ks][0], sf[i][2 * ks][1],
                       sf[i][2 * ks][2], sf[i][2 * ks][3]);
        u.u[1] = pack4(sf[i][2 * ks + 1][0], sf[i][2 * ks + 1][1],
                       sf[i][2 * ks + 1][2], sf[i][2 * ks + 1][3]);
        pa[i][ks] = u.v;
      }
    }
    // O += P * V
    __builtin_amdgcn_s_setprio(1);
#pragma unroll
    for (int n = 0; n < 4; ++n)
#pragma unroll
      for (int i = 0; i < 2; ++i) {
        oacc[i][n] = MFMA(pa[i][0], vf0[n], oacc[i][n]);
        oacc[i][n] = MFMA(pa[i][1], vf1[n], oacc[i][n]);
      }
    __builtin_amdgcn_s_setprio(0);
  };

  stage(0, 0);
  stage(1, 1);
  for (int j = 0; j < 8; ++j) {
    const int base = (j & 1) << 1;
    asm volatile("s_waitcnt vmcnt(0)" ::: "memory");
    __builtin_amdgcn_s_barrier();
    __builtin_amdgcn_sched_barrier(0);
    if (j < 7) {
      stage(base ^ 2, 2 * j + 2);
      stage((base ^ 2) + 1, 2 * j + 3);
    }
    tile(KsP(g, base), g * 1024 + (2 * j) * 64);
    tile(KsP(g, base + 1), g * 1024 + (2 * j + 1) * 64);
  }

  // finalize l: sum the 4 hi-groups (lanes sharing lane&15)
  float lfin[2];
#pragma unroll
  for (int i = 0; i < 2; ++i) {
    float t = lsum[i] + __shfl_xor(lsum[i], 16, 64);
    lfin[i] = t + __shfl_xor(t, 32, 64);
  }

  // ---- combine the two k-halves through LDS (exact f32 add) ----
  __syncthreads();  // all compute done; safe to overwrite K LDS
  float* Ol = (float*)smem;            // [128][68] f32 (pad 68 -> free 2-way)
  float* l1 = (float*)(smem + 34816);  // [128] f32 (g==1 partial l)
  float* l0 = (float*)(smem + 35328);  // [128] f32 (g==0 partial l)

  if (g == 1) {
#pragma unroll
    for (int i = 0; i < 2; ++i)
#pragma unroll
      for (int r = 0; r < 4; ++r) {
        const int q = wg * 32 + i * 16 + ((lane >> 4) << 2) + r;
#pragma unroll
        for (int n = 0; n < 4; ++n)
          Ol[q * 68 + n * 16 + (lane & 15)] = oacc[i][n][r];
      }
    if (lane < 16) {
      l1[wg * 32 + lane]      = lfin[0];
      l1[wg * 32 + 16 + lane] = lfin[1];
    }
  } else {
    if (lane < 16) {
      l0[wg * 32 + lane]      = lfin[0];
      l0[wg * 32 + 16 + lane] = lfin[1];
    }
  }
  __syncthreads();
  if (g == 0) {
    const int b2 = bh >> 3, h2 = bh & 7;
#pragma unroll
    for (int i = 0; i < 2; ++i)
#pragma unroll
      for (int r = 0; r < 4; ++r) {
        const int q  = wg * 32 + i * 16 + ((lane >> 4) << 2) + r;
        const float rl = 1.0f / (l0[q] + l1[q]);
        const int qrow = qt + q;
#pragma unroll
        for (int n = 0; n < 4; ++n) {
          const int s = n * 16 + (lane & 15);
          const float o = oacc[i][n][r] + Ol[q * 68 + s];
          a_h[(size_t)(b2 * 2048 + qrow) * 512 + h2 * 64 + s] = (f16)(o * rl);
        }
      }
  }
}

// ---------------- kernel 3: output projection + bias ----------------
__global__ __launch_bounds__(256) void k_gemm_out(
    const f16* __restrict__ A, const f16* __restrict__ B,
    const float* __restrict__ bo, float* __restrict__ out) {
  const int bm = blockIdx.x * 128;
  const int bn = blockIdx.y * 128;
  f32x4 acc[4][4] = {};
  gemm_core(A, B, bm, bn, acc);

  const int tid  = threadIdx.x;
  const int lane = tid & 63;
  const int w    = tid >> 6;
  const int wr   = (w >> 1) & 1, wc = w & 1;
#pragma unroll
  for (int i = 0; i < 4; ++i) {
    const int m0 = bm + wr * 64 + i * 16 + ((lane >> 4) << 2);
#pragma unroll
    for (int j = 0; j < 4; ++j) {
      const int n = bn + wc * 64 + j * 16 + (lane & 15);
      const float bias = bo[n];
#pragma unroll
      for (int r = 0; r < 4; ++r)
        out[(size_t)(m0 + r) * 512 + n] = acc[i][j][r] + bias;
    }
  }
}

// ---------------- launch ----------------
extern "C" void kernel_launch(void* const* d_in, const int* in_sizes, int n_in,
                              void* d_out, int out_size, void* d_ws, size_t ws_size,
                              hipStream_t stream) {
  const float* x  = (const float*)d_in[0];
  const float* Wq = (const float*)d_in[1];
  const float* Wk = (const float*)d_in[2];
  const float* Wv = (const float*)d_in[3];
  const float* Wo = (const float*)d_in[4];
  const float* bo = (const float*)d_in[5];
  float* out = (float*)d_out;

  char* ws = (char*)d_ws;
  f16* x_h    = (f16*)(ws);
  f16* wqkv_h = (f16*)(ws + 8388608);
  f16* wo_h   = (f16*)(ws + 9961472);
  f16* q_h    = (f16*)(ws + 10485760);
  f16* k_h    = (f16*)(ws + 18874368);
  f16* vt_h   = (f16*)(ws + 27262976);
  f16* a_h    = (f16*)(ws + 35651584);
  (void)ws_size; (void)in_sizes; (void)n_in; (void)out_size;

  k_convert<<<2048, 256, 0, stream>>>(x, Wq, Wk, Wv, Wo, x_h, wqkv_h, wo_h);
  k_gemm_qkv<<<dim3(64, 12), 256, 0, stream>>>(x_h, wqkv_h, q_h, k_h, vt_h);
  k_attn<<<512, 512, 0, stream>>>(q_h, k_h, vt_h, a_h);
  k_gemm_out<<<dim3(64, 4), 256, 0, stream>>>(a_h, wo_h, bo, out);
}

// Round 11
// 85.836 us; speedup vs baseline: 1.3983x; 1.3983x over previous
//
#include <hip/hip_runtime.h>

typedef _Float16 f16;
typedef _Float16 f16x8 __attribute__((ext_vector_type(8)));
typedef _Float16 f16x4 __attribute__((ext_vector_type(4)));
typedef float    f32x4 __attribute__((ext_vector_type(4)));
typedef __fp16   fp16x2 __attribute__((ext_vector_type(2)));

#define MFMA(a,b,c) __builtin_amdgcn_mfma_f32_16x16x32_f16((a),(b),(c),0,0,0)

#if __has_builtin(__builtin_amdgcn_exp2f)
#define EXP2(x) __builtin_amdgcn_exp2f(x)
#else
#define EXP2(x) exp2f(x)
#endif

// async global->LDS, 16B per lane. ldsptr must be wave-uniform; lane i lands at ldsptr + i*16.
__device__ __forceinline__ void gl_lds16(const void* g, void* l) {
  __builtin_amdgcn_global_load_lds(
      (__attribute__((address_space(1))) void*)(void*)(g),
      (__attribute__((address_space(3))) void*)(l),
      16, 0, 0);
}

// LDS column swizzle: uses row bits 0,1,3 -> uniform 8-way 16B-unit spread for
// both the rho-ordered kf reads and the linear vf reads.
__device__ __forceinline__ int SWZ(int row) {
  return ((row & 3) | ((row >> 1) & 4)) << 4;
}

// ---------------- kernel 0: fp32 -> fp16 conversion / packing ----------------
__global__ __launch_bounds__(256) void k_convert(
    const float* __restrict__ x, const float* __restrict__ Wq,
    const float* __restrict__ Wk, const float* __restrict__ Wv,
    const float* __restrict__ Wo,
    f16* __restrict__ x_h, f16* __restrict__ wqkv_h, f16* __restrict__ wo_h) {
  const int XQ    = (8192 * 512) / 4;
  const int WQKVQ = (1536 * 512) / 4;
  const int WOQ   = (512 * 512) / 4;
  const int total = XQ + WQKVQ + WOQ;
  for (int q = blockIdx.x * blockDim.x + threadIdx.x; q < total;
       q += gridDim.x * blockDim.x) {
    const float* src;
    f16* dst;
    if (q < XQ) {
      src = x + q * 4;
      dst = x_h + q * 4;
    } else if (q < XQ + WQKVQ) {
      int j  = q - XQ;
      int r  = j >> 7;
      int c0 = (j & 127) * 4;
      const float* w = (r < 512) ? Wq : (r < 1024) ? Wk : Wv;
      src = w + (r & 511) * 512 + c0;
      dst = wqkv_h + j * 4;
    } else {
      int j = q - XQ - WQKVQ;
      src = Wo + j * 4;
      dst = wo_h + j * 4;
    }
    float4 v = *(const float4*)src;
    f16x4 o = {(f16)v.x, (f16)v.y, (f16)v.z, (f16)v.w};
    *(f16x4*)dst = o;
  }
}

// ---------------- shared GEMM core: C(128x128) += A[128xK] * B[128xK]^T ------
// Double-buffered LDS, single barrier per K-step, stage issued under compute.
__device__ __forceinline__ void gemm_core(const f16* __restrict__ A,
                                          const f16* __restrict__ B,
                                          int bm, int bn, f32x4 (&acc)[4][4]) {
  __shared__ f16 As[2][128 * 64];
  __shared__ f16 Bs[2][128 * 64];
  const int tid  = threadIdx.x;
  const int lane = tid & 63;
  const int w    = tid >> 6;
  const int wr   = (w >> 1) & 1, wc = w & 1;
  const int r0   = tid >> 3;
  const int cb   = (tid & 7) << 4;

  auto stage = [&](int buf, int kt) {
#pragma unroll
    for (int inst = 0; inst < 4; ++inst) {
      const int row  = inst * 32 + r0;
      const int csrc = cb ^ ((row & 7) << 4);
      gl_lds16(A + (bm + row) * 512 + kt + (csrc >> 1),
               (char*)As[buf] + inst * 4096 + w * 1024);
      gl_lds16(B + (bn + row) * 512 + kt + (csrc >> 1),
               (char*)Bs[buf] + inst * 4096 + w * 1024);
    }
  };

  stage(0, 0);
#pragma unroll
  for (int t = 0; t < 8; ++t) {
    const int cur = t & 1;
    asm volatile("s_waitcnt vmcnt(0)" ::: "memory");
    __builtin_amdgcn_s_barrier();
    __builtin_amdgcn_sched_barrier(0);
    if (t < 7) stage(cur ^ 1, (t + 1) * 64);
    f16x8 af[4][2], bf[4][2];
#pragma unroll
    for (int i = 0; i < 4; ++i) {
      const int ra = wr * 64 + i * 16 + (lane & 15);
      const int rb = wc * 64 + i * 16 + (lane & 15);
#pragma unroll
      for (int ks = 0; ks < 2; ++ks) {
        const int cc = ks * 64 + ((lane >> 4) << 4);
        af[i][ks] = *(const f16x8*)((const char*)As[cur] + ra * 128 + (cc ^ ((ra & 7) << 4)));
        bf[i][ks] = *(const f16x8*)((const char*)Bs[cur] + rb * 128 + (cc ^ ((rb & 7) << 4)));
      }
    }
    __builtin_amdgcn_s_setprio(1);
#pragma unroll
    for (int i = 0; i < 4; ++i)
#pragma unroll
      for (int j = 0; j < 4; ++j) {
        acc[i][j] = MFMA(af[i][0], bf[j][0], acc[i][j]);
        acc[i][j] = MFMA(af[i][1], bf[j][1], acc[i][j]);
      }
    __builtin_amdgcn_s_setprio(0);
  }
}

// ---------------- kernel 1: QKV projection ----------------
// Q scaled by log2(e)/sqrt(512); Q,K -> [b,h,t,s]; V -> [b,h,s,t] (plain t).
__global__ __launch_bounds__(256) void k_gemm_qkv(
    const f16* __restrict__ A, const f16* __restrict__ B,
    f16* __restrict__ q_h, f16* __restrict__ k_h, f16* __restrict__ vt_h) {
  const int bm = blockIdx.x * 128;
  const int bn = blockIdx.y * 128;
  f32x4 acc[4][4] = {};
  gemm_core(A, B, bm, bn, acc);

  const int tid  = threadIdx.x;
  const int lane = tid & 63;
  const int w    = tid >> 6;
  const int wr   = (w >> 1) & 1, wc = w & 1;
  const float qscale = 0.044194173824159216f * 1.4426950408889634f;
#pragma unroll
  for (int i = 0; i < 4; ++i) {
    const int m0 = bm + wr * 64 + i * 16 + ((lane >> 4) << 2);
#pragma unroll
    for (int j = 0; j < 4; ++j) {
      const int n   = bn + wc * 64 + j * 16 + (lane & 15);
      const int sec = n >> 9;
      const int nn  = n & 511;
      const int h   = nn >> 6, s = nn & 63;
#pragma unroll
      for (int r = 0; r < 4; ++r) {
        const int m = m0 + r;
        const int b = m >> 11, t = m & 2047;
        const int bh = b * 8 + h;
        const float v = acc[i][j][r];
        if (sec == 0)
          q_h[(bh * 2048 + t) * 64 + s] = (f16)(v * qscale);
        else if (sec == 1)
          k_h[(bh * 2048 + t) * 64 + s] = (f16)v;
        else
          vt_h[(bh * 64 + s) * 2048 + t] = (f16)v;
      }
    }
  }
}

// ---------------- kernel 2: flash attention ----------------------------------
// In-register P (swapped QK^T + rho K-row order), fat waves + K-split:
// 8 waves = 2 k-groups x 4 waves; each wave owns 64 q-rows (4 fragments) so
// kf/vf LDS reads amortize 2x (LDS-read pipe 20.5 -> 10.2 us/CU); group g
// covers keys [g*1024, g*1024+1024). V staged in LDS (r10's direct-global
// V was uncoalesced - 16 scattered 64B segments/instr). Combine = exact f32
// add in LDS, two 128-row passes. Grid 256 = 1 block/CU, 2 waves/SIMD.
__global__ __launch_bounds__(512, 2) void k_attn(
    const f16* __restrict__ q_h, const f16* __restrict__ k_h,
    const f16* __restrict__ vt_h, f16* __restrict__ a_h) {
  __shared__ char smem[65536];  // [g]{ [buf]{K 8KB, V 8KB} x2 } = 2x32KB; combine reuses

  const int tid  = threadIdx.x;
  const int lane = tid & 63;
  const int w    = tid >> 6;
  const int g    = w >> 2;   // k-half
  const int wg   = w & 3;    // wave within group

  int id = blockIdx.x;
  id = (id & 7) * 32 + (id >> 3);     // XCD chunking (256 = 8*32, bijective)
  const int qt = (id & 7) * 256;
  const int bh = id >> 3;

  const f16* qb = q_h + (size_t)bh * 2048 * 64;
  const f16* kb = k_h + (size_t)bh * 2048 * 64;
  const f16* vb = vt_h + (size_t)bh * 64 * 2048;

  auto KsP = [&](int grp, int buf) { return smem + grp * 32768 + buf * 16384; };
  auto VsP = [&](int grp, int buf) { return smem + grp * 32768 + buf * 16384 + 8192; };

  const int m  = lane & 15;
  const int hi = lane >> 4;

  f16x8 qf[4][2];
#pragma unroll
  for (int i = 0; i < 4; ++i) {
    const int qrow = qt + wg * 64 + i * 16 + m;
#pragma unroll
    for (int ks = 0; ks < 2; ++ks)
      qf[i][ks] = *(const f16x8*)(qb + qrow * 64 + ks * 32 + hi * 8);
  }

  f32x4 oacc[4][4] = {};
  f32x4 lrun[4]    = {};

  const int gt  = tid & 255;        // group-local tid
  const int r0  = gt >> 3;          // 0..31
  const int cbb = (tid & 7) << 4;

  const f16 one = (f16)1.0f;
  const f16x8 ones = {one, one, one, one, one, one, one, one};

  auto stage = [&](int buf, int t) {
    const int ktv = g * 1024 + t * 64;
#pragma unroll
    for (int inst = 0; inst < 2; ++inst) {
      const int row  = inst * 32 + r0;
      const int csrc = cbb ^ SWZ(row);
      gl_lds16(kb + (ktv + row) * 64 + (csrc >> 1),
               KsP(g, buf) + inst * 4096 + wg * 1024);
      gl_lds16(vb + row * 2048 + ktv + (csrc >> 1),
               VsP(g, buf) + inst * 4096 + wg * 1024);
    }
  };

  auto pack4 = [](float a, float b, float c, float d) -> unsigned long long {
    union { fp16x2 h2[2]; unsigned long long u; } t;
    t.h2[0] = __builtin_amdgcn_cvt_pkrtz(a, b);
    t.h2[1] = __builtin_amdgcn_cvt_pkrtz(c, d);
    return t.u;
  };

  auto tile = [&](const char* ksb, const char* vsb) {
    // K fragments in rho order rho(n,m)=32(n>>1)+8(m>>2)+4(n&1)+(m&3)
    f16x8 kf[4][2];
#pragma unroll
    for (int n = 0; n < 4; ++n) {
      const int row = ((n >> 1) << 5) + ((m >> 2) << 3) + ((n & 1) << 2) + (m & 3);
      const int sw  = SWZ(row);
#pragma unroll
      for (int ks = 0; ks < 2; ++ks) {
        const int c = (ks * 64 + (hi << 4)) ^ sw;
        kf[n][ks] = *(const f16x8*)(ksb + row * 128 + c);
      }
    }
    // S^T = K Q^T (swapped operands); 16 independent chains for MFMA ILP
    f32x4 sf[4][4];
    __builtin_amdgcn_s_setprio(1);
#pragma unroll
    for (int i = 0; i < 4; ++i)
#pragma unroll
      for (int n = 0; n < 4; ++n) {
        f32x4 s = {0.f, 0.f, 0.f, 0.f};
        s = MFMA(kf[n][0], qf[i][0], s);
        s = MFMA(kf[n][1], qf[i][1], s);
        sf[i][n] = s;
      }
    __builtin_amdgcn_s_setprio(0);
    // P = exp2(S), packed in-lane into PV A-fragments (true k order)
    f16x8 pa[4][2];
#pragma unroll
    for (int i = 0; i < 4; ++i)
#pragma unroll
      for (int ks = 0; ks < 2; ++ks) {
        union { unsigned long long u[2]; f16x8 v; } u;
        u.u[0] = pack4(EXP2(sf[i][2 * ks][0]), EXP2(sf[i][2 * ks][1]),
                       EXP2(sf[i][2 * ks][2]), EXP2(sf[i][2 * ks][3]));
        u.u[1] = pack4(EXP2(sf[i][2 * ks + 1][0]), EXP2(sf[i][2 * ks + 1][1]),
                       EXP2(sf[i][2 * ks + 1][2]), EXP2(sf[i][2 * ks + 1][3]));
        pa[i][ks] = u.v;
      }
    // l += P * ones ; O += P * V
    __builtin_amdgcn_s_setprio(1);
#pragma unroll
    for (int i = 0; i < 4; ++i) {
      lrun[i] = MFMA(pa[i][0], ones, lrun[i]);
      lrun[i] = MFMA(pa[i][1], ones, lrun[i]);
    }
#pragma unroll
    for (int n = 0; n < 4; ++n) {
      const int row = n * 16 + m;
      const int sw  = SWZ(row);
      const f16x8 vf0 = *(const f16x8*)(vsb + row * 128 + ((hi << 4) ^ sw));
      const f16x8 vf1 = *(const f16x8*)(vsb + row * 128 + ((64 + (hi << 4)) ^ sw));
#pragma unroll
      for (int i = 0; i < 4; ++i) {
        oacc[i][n] = MFMA(pa[i][0], vf0, oacc[i][n]);
        oacc[i][n] = MFMA(pa[i][1], vf1, oacc[i][n]);
      }
    }
    __builtin_amdgcn_s_setprio(0);
  };

  stage(0, 0);
  for (int j = 0; j < 16; ++j) {
    const int cur = j & 1;
    asm volatile("s_waitcnt vmcnt(0)" ::: "memory");
    __builtin_amdgcn_s_barrier();
    __builtin_amdgcn_sched_barrier(0);
    if (j < 15) stage(cur ^ 1, j + 1);
    tile(KsP(g, cur), VsP(g, cur));
  }

  // ---- combine the two k-halves through LDS, two 128-row passes ----
  __syncthreads();  // all compute done; safe to overwrite K/V LDS
  float* Ol = (float*)smem;            // [128][68] f32 (pad 68 -> free 2-way)
  float* l1 = (float*)(smem + 34816);  // [128] f32

  const int b2 = bh >> 3, h2 = bh & 7;
#pragma unroll
  for (int p = 0; p < 2; ++p) {
    if (g == 1 && (wg >> 1) == p) {
#pragma unroll
      for (int i = 0; i < 4; ++i)
#pragma unroll
        for (int r = 0; r < 4; ++r) {
          const int ql = (wg * 64 + i * 16 + hi * 4 + r) & 127;
#pragma unroll
          for (int n = 0; n < 4; ++n)
            Ol[ql * 68 + n * 16 + m] = oacc[i][n][r];
          if (m == 0) l1[ql] = lrun[i][r];
        }
    }
    __syncthreads();
    if (g == 0 && (wg >> 1) == p) {
#pragma unroll
      for (int i = 0; i < 4; ++i)
#pragma unroll
        for (int r = 0; r < 4; ++r) {
          const int qg = wg * 64 + i * 16 + hi * 4 + r;
          const int ql = qg & 127;
          const float rl = 1.0f / (lrun[i][r] + l1[ql]);
          const int qrow = qt + qg;
#pragma unroll
          for (int n = 0; n < 4; ++n) {
            const int s = n * 16 + m;
            const float o = oacc[i][n][r] + Ol[ql * 68 + s];
            a_h[(size_t)(b2 * 2048 + qrow) * 512 + h2 * 64 + s] = (f16)(o * rl);
          }
        }
    }
    __syncthreads();
  }
}

// ---------------- kernel 3: output projection + bias ----------------
__global__ __launch_bounds__(256) void k_gemm_out(
    const f16* __restrict__ A, const f16* __restrict__ B,
    const float* __restrict__ bo, float* __restrict__ out) {
  const int bm = blockIdx.x * 128;
  const int bn = blockIdx.y * 128;
  f32x4 acc[4][4] = {};
  gemm_core(A, B, bm, bn, acc);

  const int tid  = threadIdx.x;
  const int lane = tid & 63;
  const int w    = tid >> 6;
  const int wr   = (w >> 1) & 1, wc = w & 1;
#pragma unroll
  for (int i = 0; i < 4; ++i) {
    const int m0 = bm + wr * 64 + i * 16 + ((lane >> 4) << 2);
#pragma unroll
    for (int j = 0; j < 4; ++j) {
      const int n = bn + wc * 64 + j * 16 + (lane & 15);
      const float bias = bo[n];
#pragma unroll
      for (int r = 0; r < 4; ++r)
        out[(size_t)(m0 + r) * 512 + n] = acc[i][j][r] + bias;
    }
  }
}

// ---------------- launch ----------------
extern "C" void kernel_launch(void* const* d_in, const int* in_sizes, int n_in,
                              void* d_out, int out_size, void* d_ws, size_t ws_size,
                              hipStream_t stream) {
  const float* x  = (const float*)d_in[0];
  const float* Wq = (const float*)d_in[1];
  const float* Wk = (const float*)d_in[2];
  const float* Wv = (const float*)d_in[3];
  const float* Wo = (const float*)d_in[4];
  const float* bo = (const float*)d_in[5];
  float* out = (float*)d_out;

  char* ws = (char*)d_ws;
  f16* x_h    = (f16*)(ws);
  f16* wqkv_h = (f16*)(ws + 8388608);
  f16* wo_h   = (f16*)(ws + 9961472);
  f16* q_h    = (f16*)(ws + 10485760);
  f16* k_h    = (f16*)(ws + 18874368);
  f16* vt_h   = (f16*)(ws + 27262976);
  f16* a_h    = (f16*)(ws + 35651584);
  (void)ws_size; (void)in_sizes; (void)n_in; (void)out_size;

  k_convert<<<2048, 256, 0, stream>>>(x, Wq, Wk, Wv, Wo, x_h, wqkv_h, wo_h);
  k_gemm_qkv<<<dim3(64, 12), 256, 0, stream>>>(x_h, wqkv_h, q_h, k_h, vt_h);
  k_attn<<<256, 512, 0, stream>>>(q_h, k_h, vt_h, a_h);
  k_gemm_out<<<dim3(64, 4), 256, 0, stream>>>(a_h, wo_h, bo, out);
}

// Round 12
// 80.427 us; speedup vs baseline: 1.4923x; 1.0672x over previous
//
#include <hip/hip_runtime.h>

typedef _Float16 f16;
typedef _Float16 f16x8 __attribute__((ext_vector_type(8)));
typedef _Float16 f16x4 __attribute__((ext_vector_type(4)));
typedef float    f32x4 __attribute__((ext_vector_type(4)));
typedef __fp16   fp16x2 __attribute__((ext_vector_type(2)));

#define MFMA(a,b,c) __builtin_amdgcn_mfma_f32_16x16x32_f16((a),(b),(c),0,0,0)

#if __has_builtin(__builtin_amdgcn_exp2f)
#define EXP2(x) __builtin_amdgcn_exp2f(x)
#else
#define EXP2(x) exp2f(x)
#endif

// async global->LDS, 16B per lane. ldsptr must be wave-uniform; lane i lands at ldsptr + i*16.
__device__ __forceinline__ void gl_lds16(const void* g, void* l) {
  __builtin_amdgcn_global_load_lds(
      (__attribute__((address_space(1))) void*)(void*)(g),
      (__attribute__((address_space(3))) void*)(l),
      16, 0, 0);
}

// LDS column swizzle: uses row bits 0,1,3 -> uniform 8-way 16B-unit spread for
// both the rho-ordered kf reads and the linear vf reads.
__device__ __forceinline__ int SWZ(int row) {
  return ((row & 3) | ((row >> 1) & 4)) << 4;
}

// ---------------- kernel 0: fp32 -> fp16 conversion / packing ----------------
__global__ __launch_bounds__(256) void k_convert(
    const float* __restrict__ x, const float* __restrict__ Wq,
    const float* __restrict__ Wk, const float* __restrict__ Wv,
    const float* __restrict__ Wo,
    f16* __restrict__ x_h, f16* __restrict__ wqkv_h, f16* __restrict__ wo_h) {
  const int XQ    = (8192 * 512) / 4;
  const int WQKVQ = (1536 * 512) / 4;
  const int WOQ   = (512 * 512) / 4;
  const int total = XQ + WQKVQ + WOQ;
  for (int q = blockIdx.x * blockDim.x + threadIdx.x; q < total;
       q += gridDim.x * blockDim.x) {
    const float* src;
    f16* dst;
    if (q < XQ) {
      src = x + q * 4;
      dst = x_h + q * 4;
    } else if (q < XQ + WQKVQ) {
      int j  = q - XQ;
      int r  = j >> 7;
      int c0 = (j & 127) * 4;
      const float* w = (r < 512) ? Wq : (r < 1024) ? Wk : Wv;
      src = w + (r & 511) * 512 + c0;
      dst = wqkv_h + j * 4;
    } else {
      int j = q - XQ - WQKVQ;
      src = Wo + j * 4;
      dst = wo_h + j * 4;
    }
    float4 v = *(const float4*)src;
    f16x4 o = {(f16)v.x, (f16)v.y, (f16)v.z, (f16)v.w};
    *(f16x4*)dst = o;
  }
}

// ---------------- shared GEMM core: C(128x128) += A[128xK] * B[128xK]^T ------
// Double-buffered LDS (in caller-provided smem), single barrier per K-step,
// stage issued under compute.
__device__ __forceinline__ void gemm_core(const f16* __restrict__ A,
                                          const f16* __restrict__ B,
                                          int bm, int bn, f32x4 (&acc)[4][4],
                                          char* smem) {
  f16* As = (f16*)smem;             // [2][128*64]
  f16* Bs = (f16*)(smem + 32768);   // [2][128*64]
  const int tid  = threadIdx.x;
  const int lane = tid & 63;
  const int w    = tid >> 6;
  const int wr   = (w >> 1) & 1, wc = w & 1;
  const int r0   = tid >> 3;
  const int cb   = (tid & 7) << 4;

  auto stage = [&](int buf, int kt) {
#pragma unroll
    for (int inst = 0; inst < 4; ++inst) {
      const int row  = inst * 32 + r0;
      const int csrc = cb ^ ((row & 7) << 4);
      gl_lds16(A + (bm + row) * 512 + kt + (csrc >> 1),
               (char*)As + buf * 16384 + inst * 4096 + w * 1024);
      gl_lds16(B + (bn + row) * 512 + kt + (csrc >> 1),
               (char*)Bs + buf * 16384 + inst * 4096 + w * 1024);
    }
  };

  stage(0, 0);
#pragma unroll
  for (int t = 0; t < 8; ++t) {
    const int cur = t & 1;
    asm volatile("s_waitcnt vmcnt(0)" ::: "memory");
    __builtin_amdgcn_s_barrier();
    __builtin_amdgcn_sched_barrier(0);
    if (t < 7) stage(cur ^ 1, (t + 1) * 64);
    f16x8 af[4][2], bf[4][2];
#pragma unroll
    for (int i = 0; i < 4; ++i) {
      const int ra = wr * 64 + i * 16 + (lane & 15);
      const int rb = wc * 64 + i * 16 + (lane & 15);
#pragma unroll
      for (int ks = 0; ks < 2; ++ks) {
        const int cc = ks * 64 + ((lane >> 4) << 4);
        af[i][ks] = *(const f16x8*)((const char*)As + cur * 16384 + ra * 128 + (cc ^ ((ra & 7) << 4)));
        bf[i][ks] = *(const f16x8*)((const char*)Bs + cur * 16384 + rb * 128 + (cc ^ ((rb & 7) << 4)));
      }
    }
    __builtin_amdgcn_s_setprio(1);
#pragma unroll
    for (int i = 0; i < 4; ++i)
#pragma unroll
      for (int j = 0; j < 4; ++j) {
        acc[i][j] = MFMA(af[i][0], bf[j][0], acc[i][j]);
        acc[i][j] = MFMA(af[i][1], bf[j][1], acc[i][j]);
      }
    __builtin_amdgcn_s_setprio(0);
  }
}

// ---------------- kernel 1: QKV projection ----------------
// Q scaled by log2(e)/sqrt(512); Q,K -> [b,h,t,s]; V -> [b,h,s,t].
// V blocks (bn>=1024) run gemm_core with swapped operands so acc is already
// transposed ([s][t]); then ALL blocks funnel acc through an LDS f16 tile
// T[128][136] and emit fully-coalesced f16x8 stores (the old per-element
// scatter was 2B stores at 4KB stride for V: ~32x write amplification).
__global__ __launch_bounds__(256) void k_gemm_qkv(
    const f16* __restrict__ A, const f16* __restrict__ B,
    f16* __restrict__ q_h, f16* __restrict__ k_h, f16* __restrict__ vt_h) {
  __shared__ char smem[65536];
  const int bm = blockIdx.x * 128;
  const int bn = blockIdx.y * 128;
  const bool isV = (bn >= 1024);

  f32x4 acc[4][4] = {};
  if (isV) gemm_core(B, A, bn, bm, acc, smem);   // acc = C^T tile [n][m]
  else     gemm_core(A, B, bm, bn, acc, smem);   // acc = C tile [m][n]

  const int tid  = threadIdx.x;
  const int lane = tid & 63;
  const int w    = tid >> 6;
  const int wr   = (w >> 1) & 1, wc = w & 1;
  const float qscale = (bn < 512) ? 0.044194173824159216f * 1.4426950408889634f : 1.0f;

  __syncthreads();               // staging buffers done being read
  f16* T = (f16*)smem;           // [128][136] f16 (pad 8 -> aligned b128 rows)
#pragma unroll
  for (int i = 0; i < 4; ++i) {
    const int rr = wr * 64 + i * 16 + ((lane >> 4) << 2);
#pragma unroll
    for (int j = 0; j < 4; ++j) {
      const int cc = wc * 64 + j * 16 + (lane & 15);
#pragma unroll
      for (int r = 0; r < 4; ++r)
        T[(rr + r) * 136 + cc] = (f16)(acc[i][j][r] * qscale);
    }
  }
  __syncthreads();

  f16* dst_qk = (bn < 512) ? q_h : k_h;
#pragma unroll
  for (int k = 0; k < 8; ++k) {
    const int idx  = k * 256 + tid;
    const int row  = idx >> 4;
    const int col8 = (idx & 15) * 8;
    const f16x8 v = *(const f16x8*)(T + row * 136 + col8);
    if (!isV) {
      const int m = bm + row, b = m >> 11, t = m & 2047;
      const int nn = (bn + col8) & 511, h = nn >> 6, s = nn & 63;
      *(f16x8*)(dst_qk + ((size_t)((b * 8 + h) * 2048 + t)) * 64 + s) = v;
    } else {
      const int nn = (bn - 1024) + row, h = nn >> 6, s = nn & 63;
      const int m = bm + col8, b = m >> 11, t = m & 2047;
      *(f16x8*)(vt_h + ((size_t)((b * 8 + h) * 64 + s)) * 2048 + t) = v;
    }
  }
}

// ---------------- kernel 2: flash attention ----------------------------------
// (unchanged from round 11 — 42 us, isolated this round)
// In-register P (swapped QK^T + rho K-row order), fat waves + K-split:
// 8 waves = 2 k-groups x 4 waves; each wave owns 64 q-rows.
__global__ __launch_bounds__(512, 2) void k_attn(
    const f16* __restrict__ q_h, const f16* __restrict__ k_h,
    const f16* __restrict__ vt_h, f16* __restrict__ a_h) {
  __shared__ char smem[65536];

  const int tid  = threadIdx.x;
  const int lane = tid & 63;
  const int w    = tid >> 6;
  const int g    = w >> 2;
  const int wg   = w & 3;

  int id = blockIdx.x;
  id = (id & 7) * 32 + (id >> 3);
  const int qt = (id & 7) * 256;
  const int bh = id >> 3;

  const f16* qb = q_h + (size_t)bh * 2048 * 64;
  const f16* kb = k_h + (size_t)bh * 2048 * 64;
  const f16* vb = vt_h + (size_t)bh * 64 * 2048;

  auto KsP = [&](int grp, int buf) { return smem + grp * 32768 + buf * 16384; };
  auto VsP = [&](int grp, int buf) { return smem + grp * 32768 + buf * 16384 + 8192; };

  const int m  = lane & 15;
  const int hi = lane >> 4;

  f16x8 qf[4][2];
#pragma unroll
  for (int i = 0; i < 4; ++i) {
    const int qrow = qt + wg * 64 + i * 16 + m;
#pragma unroll
    for (int ks = 0; ks < 2; ++ks)
      qf[i][ks] = *(const f16x8*)(qb + qrow * 64 + ks * 32 + hi * 8);
  }

  f32x4 oacc[4][4] = {};
  f32x4 lrun[4]    = {};

  const int gt  = tid & 255;
  const int r0  = gt >> 3;
  const int cbb = (tid & 7) << 4;

  const f16 one = (f16)1.0f;
  const f16x8 ones = {one, one, one, one, one, one, one, one};

  auto stage = [&](int buf, int t) {
    const int ktv = g * 1024 + t * 64;
#pragma unroll
    for (int inst = 0; inst < 2; ++inst) {
      const int row  = inst * 32 + r0;
      const int csrc = cbb ^ SWZ(row);
      gl_lds16(kb + (ktv + row) * 64 + (csrc >> 1),
               KsP(g, buf) + inst * 4096 + wg * 1024);
      gl_lds16(vb + row * 2048 + ktv + (csrc >> 1),
               VsP(g, buf) + inst * 4096 + wg * 1024);
    }
  };

  auto pack4 = [](float a, float b, float c, float d) -> unsigned long long {
    union { fp16x2 h2[2]; unsigned long long u; } t;
    t.h2[0] = __builtin_amdgcn_cvt_pkrtz(a, b);
    t.h2[1] = __builtin_amdgcn_cvt_pkrtz(c, d);
    return t.u;
  };

  auto tile = [&](const char* ksb, const char* vsb) {
    f16x8 kf[4][2];
#pragma unroll
    for (int n = 0; n < 4; ++n) {
      const int row = ((n >> 1) << 5) + ((m >> 2) << 3) + ((n & 1) << 2) + (m & 3);
      const int sw  = SWZ(row);
#pragma unroll
      for (int ks = 0; ks < 2; ++ks) {
        const int c = (ks * 64 + (hi << 4)) ^ sw;
        kf[n][ks] = *(const f16x8*)(ksb + row * 128 + c);
      }
    }
    f32x4 sf[4][4];
    __builtin_amdgcn_s_setprio(1);
#pragma unroll
    for (int i = 0; i < 4; ++i)
#pragma unroll
      for (int n = 0; n < 4; ++n) {
        f32x4 s = {0.f, 0.f, 0.f, 0.f};
        s = MFMA(kf[n][0], qf[i][0], s);
        s = MFMA(kf[n][1], qf[i][1], s);
        sf[i][n] = s;
      }
    __builtin_amdgcn_s_setprio(0);
    f16x8 pa[4][2];
#pragma unroll
    for (int i = 0; i < 4; ++i)
#pragma unroll
      for (int ks = 0; ks < 2; ++ks) {
        union { unsigned long long u[2]; f16x8 v; } u;
        u.u[0] = pack4(EXP2(sf[i][2 * ks][0]), EXP2(sf[i][2 * ks][1]),
                       EXP2(sf[i][2 * ks][2]), EXP2(sf[i][2 * ks][3]));
        u.u[1] = pack4(EXP2(sf[i][2 * ks + 1][0]), EXP2(sf[i][2 * ks + 1][1]),
                       EXP2(sf[i][2 * ks + 1][2]), EXP2(sf[i][2 * ks + 1][3]));
        pa[i][ks] = u.v;
      }
    __builtin_amdgcn_s_setprio(1);
#pragma unroll
    for (int i = 0; i < 4; ++i) {
      lrun[i] = MFMA(pa[i][0], ones, lrun[i]);
      lrun[i] = MFMA(pa[i][1], ones, lrun[i]);
    }
#pragma unroll
    for (int n = 0; n < 4; ++n) {
      const int row = n * 16 + m;
      const int sw  = SWZ(row);
      const f16x8 vf0 = *(const f16x8*)(vsb + row * 128 + ((hi << 4) ^ sw));
      const f16x8 vf1 = *(const f16x8*)(vsb + row * 128 + ((64 + (hi << 4)) ^ sw));
#pragma unroll
      for (int i = 0; i < 4; ++i) {
        oacc[i][n] = MFMA(pa[i][0], vf0, oacc[i][n]);
        oacc[i][n] = MFMA(pa[i][1], vf1, oacc[i][n]);
      }
    }
    __builtin_amdgcn_s_setprio(0);
  };

  stage(0, 0);
  for (int j = 0; j < 16; ++j) {
    const int cur = j & 1;
    asm volatile("s_waitcnt vmcnt(0)" ::: "memory");
    __builtin_amdgcn_s_barrier();
    __builtin_amdgcn_sched_barrier(0);
    if (j < 15) stage(cur ^ 1, j + 1);
    tile(KsP(g, cur), VsP(g, cur));
  }

  __syncthreads();
  float* Ol = (float*)smem;
  float* l1 = (float*)(smem + 34816);

  const int b2 = bh >> 3, h2 = bh & 7;
#pragma unroll
  for (int p = 0; p < 2; ++p) {
    if (g == 1 && (wg >> 1) == p) {
#pragma unroll
      for (int i = 0; i < 4; ++i)
#pragma unroll
        for (int r = 0; r < 4; ++r) {
          const int ql = (wg * 64 + i * 16 + hi * 4 + r) & 127;
#pragma unroll
          for (int n = 0; n < 4; ++n)
            Ol[ql * 68 + n * 16 + m] = oacc[i][n][r];
          if (m == 0) l1[ql] = lrun[i][r];
        }
    }
    __syncthreads();
    if (g == 0 && (wg >> 1) == p) {
#pragma unroll
      for (int i = 0; i < 4; ++i)
#pragma unroll
        for (int r = 0; r < 4; ++r) {
          const int qg = wg * 64 + i * 16 + hi * 4 + r;
          const int ql = qg & 127;
          const float rl = 1.0f / (lrun[i][r] + l1[ql]);
          const int qrow = qt + qg;
#pragma unroll
          for (int n = 0; n < 4; ++n) {
            const int s = n * 16 + m;
            const float o = oacc[i][n][r] + Ol[ql * 68 + s];
            a_h[(size_t)(b2 * 2048 + qrow) * 512 + h2 * 64 + s] = (f16)(o * rl);
          }
        }
    }
    __syncthreads();
  }
}

// ---------------- kernel 3: output projection + bias ----------------
__global__ __launch_bounds__(256) void k_gemm_out(
    const f16* __restrict__ A, const f16* __restrict__ B,
    const float* __restrict__ bo, float* __restrict__ out) {
  __shared__ char smem[65536];
  const int bm = blockIdx.x * 128;
  const int bn = blockIdx.y * 128;
  f32x4 acc[4][4] = {};
  gemm_core(A, B, bm, bn, acc, smem);

  const int tid  = threadIdx.x;
  const int lane = tid & 63;
  const int w    = tid >> 6;
  const int wr   = (w >> 1) & 1, wc = w & 1;
#pragma unroll
  for (int i = 0; i < 4; ++i) {
    const int m0 = bm + wr * 64 + i * 16 + ((lane >> 4) << 2);
#pragma unroll
    for (int j = 0; j < 4; ++j) {
      const int n = bn + wc * 64 + j * 16 + (lane & 15);
      const float bias = bo[n];
#pragma unroll
      for (int r = 0; r < 4; ++r)
        out[(size_t)(m0 + r) * 512 + n] = acc[i][j][r] + bias;
    }
  }
}

// ---------------- launch ----------------
extern "C" void kernel_launch(void* const* d_in, const int* in_sizes, int n_in,
                              void* d_out, int out_size, void* d_ws, size_t ws_size,
                              hipStream_t stream) {
  const float* x  = (const float*)d_in[0];
  const float* Wq = (const float*)d_in[1];
  const float* Wk = (const float*)d_in[2];
  const float* Wv = (const float*)d_in[3];
  const float* Wo = (const float*)d_in[4];
  const float* bo = (const float*)d_in[5];
  float* out = (float*)d_out;

  char* ws = (char*)d_ws;
  f16* x_h    = (f16*)(ws);
  f16* wqkv_h = (f16*)(ws + 8388608);
  f16* wo_h   = (f16*)(ws + 9961472);
  f16* q_h    = (f16*)(ws + 10485760);
  f16* k_h    = (f16*)(ws + 18874368);
  f16* vt_h   = (f16*)(ws + 27262976);
  f16* a_h    = (f16*)(ws + 35651584);
  (void)ws_size; (void)in_sizes; (void)n_in; (void)out_size;

  k_convert<<<2048, 256, 0, stream>>>(x, Wq, Wk, Wv, Wo, x_h, wqkv_h, wo_h);
  k_gemm_qkv<<<dim3(64, 12), 256, 0, stream>>>(x_h, wqkv_h, q_h, k_h, vt_h);
  k_attn<<<256, 512, 0, stream>>>(q_h, k_h, vt_h, a_h);
  k_gemm_out<<<dim3(64, 4), 256, 0, stream>>>(a_h, wo_h, bo, out);
}